// Round 1
// baseline (428.762 us; speedup 1.0000x reference)
//
#include <hip/hip_runtime.h>
#include <hip/hip_bf16.h>

typedef __bf16 bf16;
typedef __bf16 bf16x4 __attribute__((ext_vector_type(4)));
typedef __bf16 bf16x8 __attribute__((ext_vector_type(8)));
typedef float  f32x4  __attribute__((ext_vector_type(4)));

// ---------------------------------------------------------------------------
// prep_w: fold Haar linearity + W into bf16 weights.
// Wbf layout: [o][1280]:
//   cols 0:256            = W1 (identity path, y1 GEMM K=256)
//   cols 256+tap*256+c    = 0.5*(±W2 ±W3 ±W4)   tap: 0=p,1=q,2=r,3=s
// so z[o][coarse] = sum_{tap,c} Wf[o][tap*256+c] * x[c][fine(tap)]  (K=1024)
__global__ __launch_bounds__(256) void prep_w(const float* __restrict__ w,
                                              bf16* __restrict__ wb) {
    const int o = blockIdx.x, c = threadIdx.x;   // grid 256 x 256
    const float* wr = w + o * 1024;
    const float w1 = wr[c], w2 = wr[256 + c], w3 = wr[512 + c], w4 = wr[768 + c];
    bf16* wo_ = wb + o * 1280;
    wo_[c]              = (bf16)w1;
    wo_[256 + 0*256 + c] = (bf16)(0.5f * ( w2 + w3 + w4));   // p
    wo_[256 + 1*256 + c] = (bf16)(0.5f * ( w2 - w3 - w4));   // q
    wo_[256 + 2*256 + c] = (bf16)(0.5f * (-w2 + w3 - w4));   // r
    wo_[256 + 3*256 + c] = (bf16)(0.5f * (-w2 - w3 + w4));   // s
}

// ---------------------------------------------------------------------------
// tile layout: [row 0..63][264 bf16], 8-elem chunks XOR-swizzled by
// (row>>2)&7 so strided row accesses spread across banks. Readers and
// writers apply the same XOR.
__device__ __forceinline__ int tix(int row, int chunk, int lo) {
    return row * 264 + (((chunk ^ ((row >> 2) & 7)) << 3) | lo);
}

// fused_x: per block (b, coarse row j, 32-wide w-tile):
//   phase1: x fp32 -> LDS tile [64 pos][256 c] bf16 via register transpose:
//           per assignment 8 channel-consecutive float4 loads (4 w-pos each)
//           -> 4 ds_write_b128. 8 vector LDS writes/thread (was 64 scalar).
//   phase2: y1 = W1 . tile       (K=256,  pos-resolution output)
//   phase3: z  = Wf . tile(taps) (K=1024, coarse-resolution output)
//           both with depth-1 W-frag pipeline from L2; barrier-free K-loops.
__global__ __launch_bounds__(256, 2) void fused_x(const float* __restrict__ x,
                                                  const bf16* __restrict__ W,
                                                  bf16* __restrict__ z,
                                                  bf16* __restrict__ y1) {
    __shared__ bf16 tile[64 * 264];
    const int bid = blockIdx.x;               // grid 2048
    const int wt = bid & 3, j = (bid >> 2) & 63, b = bid >> 8;
    const int t = threadIdx.x;
    const int w0 = wt * 32;
    const int wave = t >> 6, lane = t & 63;
    const int quad = lane >> 4, l16 = lane & 15;
    const int wo = wave * 64;

    // phase1
    #pragma unroll
    for (int it = 0; it < 2; ++it) {
        const int a   = it * 256 + t;        // 0..511 assignments
        const int c8  = a >> 4;              // chunk of 8 consecutive channels
        const int p4  = a & 15;
        const int dlt = p4 >> 3, w4 = p4 & 7;
        const float* xp = x + (((size_t)b * 256 + c8 * 8) * 128 + (2*j + dlt)) * 128
                            + w0 + w4 * 4;
        float4 v[8];
        #pragma unroll
        for (int i = 0; i < 8; ++i)
            v[i] = *(const float4*)(xp + (size_t)i * 16384);   // next channel
        #pragma unroll
        for (int e = 0; e < 4; ++e) {
            bf16x8 o8;
            #pragma unroll
            for (int i = 0; i < 8; ++i) o8[i] = (bf16)((&v[i].x)[e]);
            const int pos = dlt * 32 + w4 * 4 + e;
            *(bf16x8*)&tile[tix(pos, c8, 0)] = o8;
        }
    }

    // prefetch W1 fragments for kk=0 (L2-resident; latency hidden by barrier)
    bf16x8 wf_cur[4], wf_nxt[4];
    #pragma unroll
    for (int jj = 0; jj < 4; ++jj)
        wf_cur[jj] = *(const bf16x8*)(W +
            (size_t)(wo + jj * 16 + l16) * 1280 + quad * 8);

    __syncthreads();

    // phase2: y1 GEMM. wave = 64 pos x 64 o. MFMA(xf, wf): D.row=pos, D.col=o.
    f32x4 acc[4][4] = {};
    #pragma unroll
    for (int kk = 0; kk < 256; kk += 32) {
        if (kk < 224) {
            #pragma unroll
            for (int jj = 0; jj < 4; ++jj)
                wf_nxt[jj] = *(const bf16x8*)(W +
                    (size_t)(wo + jj * 16 + l16) * 1280 + kk + 32 + quad * 8);
        } else {
            // seed the z-loop pipeline: first Wf fragments (cols 256..)
            #pragma unroll
            for (int jj = 0; jj < 4; ++jj)
                wf_nxt[jj] = *(const bf16x8*)(W +
                    (size_t)(wo + jj * 16 + l16) * 1280 + 256 + quad * 8);
        }
        bf16x8 xf[4];
        #pragma unroll
        for (int i2 = 0; i2 < 4; ++i2)
            xf[i2] = *(const bf16x8*)&tile[tix(i2 * 16 + l16,
                                               (kk >> 3) + quad, 0)];
        #pragma unroll
        for (int i2 = 0; i2 < 4; ++i2)
            #pragma unroll
            for (int jj = 0; jj < 4; ++jj)
                acc[i2][jj] = __builtin_amdgcn_mfma_f32_16x16x32_bf16(
                    xf[i2], wf_cur[jj], acc[i2][jj], 0, 0, 0);
        #pragma unroll
        for (int jj = 0; jj < 4; ++jj) wf_cur[jj] = wf_nxt[jj];
    }

    // phase3: z GEMM, K=1024 over (tap, c). A rows = 16 coarse cols.
    // tap->fine-row: p=(0,even) q=(0,odd) r=(1,even) s=(1,odd)
    f32x4 acc2[4] = {};
    #pragma unroll
    for (int kz = 0; kz < 1024; kz += 32) {
        if (kz < 992) {
            #pragma unroll
            for (int jj = 0; jj < 4; ++jj)
                wf_nxt[jj] = *(const bf16x8*)(W +
                    (size_t)(wo + jj * 16 + l16) * 1280 + 256 + kz + 32 + quad * 8);
        }
        const int tap  = kz >> 8;
        const int trow = ((tap >> 1) << 5) | (tap & 1);
        const bf16x8 af = *(const bf16x8*)&tile[tix(trow + 2 * l16,
                                                    ((kz & 255) >> 3) + quad, 0)];
        #pragma unroll
        for (int jj = 0; jj < 4; ++jj)
            acc2[jj] = __builtin_amdgcn_mfma_f32_16x16x32_bf16(
                af, wf_cur[jj], acc2[jj], 0, 0, 0);
        #pragma unroll
        for (int jj = 0; jj < 4; ++jj) wf_cur[jj] = wf_nxt[jj];
    }

    // epilogue y1: pos = i*16+quad*4+r (4 consecutive w), o = wo+jj*16+l16
    #pragma unroll
    for (int i = 0; i < 4; ++i) {
        int p = i * 16 + quad * 4;
        int h = 2 * j + (p >> 5), wc = w0 + (p & 31);
        #pragma unroll
        for (int jj = 0; jj < 4; ++jj) {
            int o = wo + jj * 16 + l16;
            bf16x4 vv;
            #pragma unroll
            for (int r = 0; r < 4; ++r) vv[r] = (bf16)acc[i][jj][r];
            *(bf16x4*)(y1 + ((size_t)b * 256 + o) * 16384 + h * 128 + wc) = vv;
        }
    }

    // epilogue z: coarse col = wt*16 + quad*4 + r, coarse row = j
    #pragma unroll
    for (int jj = 0; jj < 4; ++jj) {
        int o = wo + jj * 16 + l16;
        bf16x4 vv;
        #pragma unroll
        for (int r = 0; r < 4; ++r) vv[r] = (bf16)acc2[jj][r];
        *(bf16x4*)(z + ((size_t)b * 256 + o) * 4096 + j * 64 + wt * 16 + quad * 4) = vv;
    }
}

// ---------------------------------------------------------------------------
// Bilinear 2x upsample weights: 0.75/0.25 per axis, edge-clamped (== jax).
__device__ __forceinline__ void load_zplane(const bf16* zp, float* zs, int t) {
    for (int i = 0; i < 2; ++i) {
        int idx = (i * 256 + t) * 8;
        int j = idx >> 6, k = idx & 63;
        bf16x8 v = *(const bf16x8*)(zp + idx);
        #pragma unroll
        for (int e = 0; e < 8; ++e) zs[j * 65 + k + e] = (float)v[e];
    }
}

__device__ __forceinline__ void up8(const float* zs, int base, float* u) {
    int h = base >> 7, w0 = base & 127;
    int j0 = h >> 1;
    int jn = (h & 1) ? min(j0 + 1, 63) : max(j0 - 1, 0);
    int K = w0 >> 1;
    float z0[6], z1[6];
    #pragma unroll
    for (int d = 0; d < 6; ++d) {
        int kc = min(max(K - 1 + d, 0), 63);
        z0[d] = zs[j0 * 65 + kc];
        z1[d] = zs[jn * 65 + kc];
    }
    #pragma unroll
    for (int e = 0; e < 8; ++e) {
        int a = (e >> 1) + 1;
        int bb = (e & 1) ? a + 1 : a - 1;
        u[e] = 0.5625f * z0[a] + 0.1875f * (z0[bb] + z1[a]) + 0.0625f * z1[bb];
    }
}

__global__ __launch_bounds__(256) void stats_k(const bf16* __restrict__ y1,
                                               const bf16* __restrict__ z,
                                               float* __restrict__ stats) {
    __shared__ float zs[64 * 65];
    __shared__ float red[8];
    const int bid = blockIdx.x;               // grid 2048 = b*256 + o
    const int o = bid & 255, b = bid >> 8;
    const int t = threadIdx.x;
    const bf16* zp = z + ((size_t)b * 256 + o) * 4096;
    const bf16* yp = y1 + ((size_t)b * 256 + o) * 16384;
    load_zplane(zp, zs, t);
    __syncthreads();
    float s = 0.f, ss = 0.f;
    for (int i = 0; i < 8; ++i) {
        int base = (i * 256 + t) * 8;
        float u[8];
        up8(zs, base, u);
        bf16x8 yv = *(const bf16x8*)(yp + base);
        #pragma unroll
        for (int e = 0; e < 8; ++e) {
            float y = (float)yv[e] + u[e];
            s += y; ss += y * y;
        }
    }
    #pragma unroll
    for (int off = 32; off > 0; off >>= 1) {
        s += __shfl_down(s, off);
        ss += __shfl_down(ss, off);
    }
    if ((t & 63) == 0) { red[t >> 6] = s; red[4 + (t >> 6)] = ss; }
    __syncthreads();
    if (t == 0) {
        atomicAdd(&stats[o],       red[0] + red[1] + red[2] + red[3]);
        atomicAdd(&stats[256 + o], red[4] + red[5] + red[6] + red[7]);
    }
}

// apply_k: finalize folded in (mean/var/scale/shift recomputed per block from
// the raw sums -- 2 scalar loads + ~6 ops, cheaper than a dispatch).
__global__ __launch_bounds__(256) void apply_k(const bf16* __restrict__ y1,
                                               const bf16* __restrict__ z,
                                               const float* __restrict__ stats,
                                               const float* __restrict__ gamma,
                                               const float* __restrict__ beta,
                                               float* __restrict__ out) {
    __shared__ float zs[64 * 65];
    const int bid = blockIdx.x;
    const int o = bid & 255, b = bid >> 8;
    const int t = threadIdx.x;
    const bf16* zp = z + ((size_t)b * 256 + o) * 4096;
    const bf16* yp = y1 + ((size_t)b * 256 + o) * 16384;
    float* op = out + ((size_t)b * 256 + o) * 16384;
    const float n = 131072.f;
    float mean = stats[o] / n;
    float var = stats[256 + o] / n - mean * mean;
    float sc = rsqrtf(var + 1e-5f) * gamma[o];
    float sh = beta[o] - mean * sc;
    load_zplane(zp, zs, t);
    __syncthreads();
    for (int i = 0; i < 8; ++i) {
        int base = (i * 256 + t) * 8;
        float u[8];
        up8(zs, base, u);
        bf16x8 yv = *(const bf16x8*)(yp + base);
        float4 o0, o1;
        o0.x = fmaxf(fmaf((float)yv[0] + u[0], sc, sh), 0.f);
        o0.y = fmaxf(fmaf((float)yv[1] + u[1], sc, sh), 0.f);
        o0.z = fmaxf(fmaf((float)yv[2] + u[2], sc, sh), 0.f);
        o0.w = fmaxf(fmaf((float)yv[3] + u[3], sc, sh), 0.f);
        o1.x = fmaxf(fmaf((float)yv[4] + u[4], sc, sh), 0.f);
        o1.y = fmaxf(fmaf((float)yv[5] + u[5], sc, sh), 0.f);
        o1.z = fmaxf(fmaf((float)yv[6] + u[6], sc, sh), 0.f);
        o1.w = fmaxf(fmaf((float)yv[7] + u[7], sc, sh), 0.f);
        *(float4*)(op + base) = o0;
        *(float4*)(op + base + 4) = o1;
    }
}

// ---------------------------------------------------------------------------
extern "C" void kernel_launch(void* const* d_in, const int* in_sizes, int n_in,
                              void* d_out, int out_size, void* d_ws, size_t ws_size,
                              hipStream_t stream) {
    const float* x      = (const float*)d_in[0];   // (8,256,128,128)
    const float* conv_w = (const float*)d_in[1];   // (256,1024)
    const float* gamma  = (const float*)d_in[2];   // (256,)
    const float* beta   = (const float*)d_in[3];   // (256,)
    float* out = (float*)d_out;

    char* ws = (char*)d_ws;
    // Wbf 640K (pad 1M) | z 16M | stats 4K (pad 64K) | y1 64M   (~81 MB)
    bf16*  Wbf   = (bf16*)ws;
    bf16*  z     = (bf16*)(ws + (1ll << 20));
    float* stats = (float*)(ws + (17ll << 20));
    bf16*  y1    = (bf16*)(ws + (17ll << 20) + (1ll << 16));

    hipMemsetAsync(stats, 0, 4096, stream);
    prep_w<<<256, 256, 0, stream>>>(conv_w, Wbf);
    fused_x<<<2048, 256, 0, stream>>>(x, Wbf, z, y1);
    stats_k<<<2048, 256, 0, stream>>>(y1, z, stats);
    apply_k<<<2048, 256, 0, stream>>>(y1, z, stats, gamma, beta, out);
}

// Round 2
// 353.594 us; speedup vs baseline: 1.2126x; 1.2126x over previous
//
#include <hip/hip_runtime.h>
#include <hip/hip_bf16.h>

typedef __bf16 bf16;
typedef __bf16 bf16x4 __attribute__((ext_vector_type(4)));
typedef __bf16 bf16x8 __attribute__((ext_vector_type(8)));
typedef float  f32x4  __attribute__((ext_vector_type(4)));

// ---------------------------------------------------------------------------
// prep_w: fold Haar linearity + W into bf16 weights.
// Wbf layout: [o][1280]:
//   cols 0:256            = W1 (identity path, y1 GEMM K=256)
//   cols 256+tap*256+c    = 0.5*(±W2 ±W3 ±W4)   tap: 0=p,1=q,2=r,3=s
// so z[o][coarse] = sum_{tap,c} Wf[o][tap*256+c] * x[c][fine(tap)]  (K=1024)
__global__ __launch_bounds__(256) void prep_w(const float* __restrict__ w,
                                              bf16* __restrict__ wb) {
    const int o = blockIdx.x, c = threadIdx.x;   // grid 256 x 256
    const float* wr = w + o * 1024;
    const float w1 = wr[c], w2 = wr[256 + c], w3 = wr[512 + c], w4 = wr[768 + c];
    bf16* wo_ = wb + o * 1280;
    wo_[c]              = (bf16)w1;
    wo_[256 + 0*256 + c] = (bf16)(0.5f * ( w2 + w3 + w4));   // p
    wo_[256 + 1*256 + c] = (bf16)(0.5f * ( w2 - w3 - w4));   // q
    wo_[256 + 2*256 + c] = (bf16)(0.5f * (-w2 + w3 - w4));   // r
    wo_[256 + 3*256 + c] = (bf16)(0.5f * (-w2 - w3 + w4));   // s
}

// ---------------------------------------------------------------------------
// LDS tile: 128 rows (fine pos = dlt*64 + w) x 256 c bf16, stride 256
// (64 KB exact). Bank spread via XOR of the 8-bf16 chunk index with
// g(row) = (row&7) ^ ((row>>2)&7):
//   phase1 writes (rows stride 4): g injective over 8 -> 2-way (free)
//   phase2 reads  (rows stride 1): perfect 2-way
//   phase3 reads  (rows stride 2): perfect 2-way
__device__ __forceinline__ int tix(int row, int chunk, int lo) {
    int g = (row & 7) ^ ((row >> 2) & 7);
    return row * 256 + (((chunk ^ g) << 3) | lo);
}

// fused_x: per block (b, coarse row j, 64-wide w-half):
//   phase1: x fp32 -> LDS tile [128 pos][256 c] bf16, 4 bursts of 8
//           channel-strided float4 loads -> register transpose -> b128 writes
//   phase2: y1 = W1 . tile   K=256, wave = 128 pos x 64 o -> 32 MFMA per
//           4 W-frag L2 loads per K-step (latency hidden by MFMA work)
//   phase2b: y1 epilogue BEFORE phase3 so acc (128 VGPR) dies early
//   phase3: z = Wf . taps    K=1024, m=32 coarse per block -> 8 MFMA + 2 LDS
//           reads per 4 W-loads; Wf L2 traffic halved vs m=16 layout
__global__ __launch_bounds__(256, 2) void fused_x(const float* __restrict__ x,
                                                  const bf16* __restrict__ W,
                                                  bf16* __restrict__ z,
                                                  bf16* __restrict__ y1) {
    __shared__ bf16 tile[128 * 256];
    const int bid = blockIdx.x;               // grid 1024 = b*128 + j*2 + half
    const int half = bid & 1, j = (bid >> 1) & 63, b = bid >> 7;
    const int t = threadIdx.x;
    const int wave = t >> 6, lane = t & 63;
    const int quad = lane >> 4, l16 = lane & 15;
    const int wo = wave * 64;

    // phase1: 32 float4/thread in 4 bursts of 8 (8 channels per burst)
    #pragma unroll
    for (int it = 0; it < 4; ++it) {
        const int a   = it * 256 + t;        // 0..1023 assignments
        const int c8  = a >> 5;              // chunk of 8 consecutive channels
        const int rem = a & 31;
        const int dlt = rem >> 4, w4 = rem & 15;
        const float* xp = x + (((size_t)b * 256 + c8 * 8) * 128 + (2*j + dlt)) * 128
                            + half * 64 + w4 * 4;
        float4 v[8];
        #pragma unroll
        for (int i = 0; i < 8; ++i)
            v[i] = *(const float4*)(xp + (size_t)i * 16384);   // next channel
        #pragma unroll
        for (int e = 0; e < 4; ++e) {
            bf16x8 o8;
            #pragma unroll
            for (int i = 0; i < 8; ++i) o8[i] = (bf16)((&v[i].x)[e]);
            const int pos = dlt * 64 + w4 * 4 + e;
            *(bf16x8*)&tile[tix(pos, c8, 0)] = o8;
        }
    }

    // prefetch W1 fragments for kk=0 (L2-resident; latency hidden by barrier)
    bf16x8 wf_cur[4], wf_nxt[4];
    #pragma unroll
    for (int jj = 0; jj < 4; ++jj)
        wf_cur[jj] = *(const bf16x8*)(W +
            (size_t)(wo + jj * 16 + l16) * 1280 + quad * 8);

    __syncthreads();

    // phase2: y1 GEMM. wave = 128 pos x 64 o. MFMA(xf, wf): D.row=pos, D.col=o
    {
        f32x4 acc[8][4] = {};
        #pragma unroll
        for (int kk = 0; kk < 256; kk += 32) {
            if (kk < 224) {
                #pragma unroll
                for (int jj = 0; jj < 4; ++jj)
                    wf_nxt[jj] = *(const bf16x8*)(W +
                        (size_t)(wo + jj * 16 + l16) * 1280 + kk + 32 + quad * 8);
            } else {
                // seed the z-loop pipeline: first Wf fragments (cols 256..)
                #pragma unroll
                for (int jj = 0; jj < 4; ++jj)
                    wf_nxt[jj] = *(const bf16x8*)(W +
                        (size_t)(wo + jj * 16 + l16) * 1280 + 256 + quad * 8);
            }
            const int kc0 = kk >> 3;
            #pragma unroll
            for (int i2 = 0; i2 < 8; ++i2) {
                const bf16x8 xf = *(const bf16x8*)&tile[tix(i2 * 16 + l16,
                                                            kc0 + quad, 0)];
                #pragma unroll
                for (int jj = 0; jj < 4; ++jj)
                    acc[i2][jj] = __builtin_amdgcn_mfma_f32_16x16x32_bf16(
                        xf, wf_cur[jj], acc[i2][jj], 0, 0, 0);
            }
            #pragma unroll
            for (int jj = 0; jj < 4; ++jj) wf_cur[jj] = wf_nxt[jj];
        }

        // y1 epilogue now (frees acc before phase3):
        // pos = i2*16 + quad*4 + r, o = wo + jj*16 + l16
        #pragma unroll
        for (int i2 = 0; i2 < 8; ++i2) {
            int p = i2 * 16 + quad * 4;
            int h = 2 * j + (p >> 6), wc = half * 64 + (p & 63);
            #pragma unroll
            for (int jj = 0; jj < 4; ++jj) {
                int o = wo + jj * 16 + l16;
                bf16x4 vv;
                #pragma unroll
                for (int r = 0; r < 4; ++r) vv[r] = (bf16)acc[i2][jj][r];
                *(bf16x4*)(y1 + ((size_t)b * 256 + o) * 16384 + h * 128 + wc) = vv;
            }
        }
    }

    // phase3: z GEMM, K=1024 over (tap, c). m = 32 coarse cols (this half).
    // tap->fine: p=(dlt0,even w) q=(dlt0,odd) r=(dlt1,even) s=(dlt1,odd)
    f32x4 acc2[2][4] = {};
    #pragma unroll
    for (int kz = 0; kz < 1024; kz += 32) {
        if (kz < 992) {
            #pragma unroll
            for (int jj = 0; jj < 4; ++jj)
                wf_nxt[jj] = *(const bf16x8*)(W +
                    (size_t)(wo + jj * 16 + l16) * 1280 + 256 + kz + 32 + quad * 8);
        }
        const int tap = kz >> 8;
        const int dlt = tap >> 1, par = tap & 1;
        const int kc0 = (kz & 255) >> 3;
        bf16x8 af[2];
        #pragma unroll
        for (int mi = 0; mi < 2; ++mi)
            af[mi] = *(const bf16x8*)&tile[tix(dlt * 64 + 2 * (mi * 16 + l16) + par,
                                               kc0 + quad, 0)];
        #pragma unroll
        for (int mi = 0; mi < 2; ++mi)
            #pragma unroll
            for (int jj = 0; jj < 4; ++jj)
                acc2[mi][jj] = __builtin_amdgcn_mfma_f32_16x16x32_bf16(
                    af[mi], wf_cur[jj], acc2[mi][jj], 0, 0, 0);
        #pragma unroll
        for (int jj = 0; jj < 4; ++jj) wf_cur[jj] = wf_nxt[jj];
    }

    // epilogue z: coarse col = half*32 + mi*16 + quad*4 + r, coarse row = j
    #pragma unroll
    for (int mi = 0; mi < 2; ++mi) {
        #pragma unroll
        for (int jj = 0; jj < 4; ++jj) {
            int o = wo + jj * 16 + l16;
            int cw = half * 32 + mi * 16 + quad * 4;
            bf16x4 vv;
            #pragma unroll
            for (int r = 0; r < 4; ++r) vv[r] = (bf16)acc2[mi][jj][r];
            *(bf16x4*)(z + ((size_t)b * 256 + o) * 4096 + j * 64 + cw) = vv;
        }
    }
}

// ---------------------------------------------------------------------------
// Bilinear 2x upsample weights: 0.75/0.25 per axis, edge-clamped (== jax).
__device__ __forceinline__ void load_zplane(const bf16* zp, float* zs, int t) {
    for (int i = 0; i < 2; ++i) {
        int idx = (i * 256 + t) * 8;
        int j = idx >> 6, k = idx & 63;
        bf16x8 v = *(const bf16x8*)(zp + idx);
        #pragma unroll
        for (int e = 0; e < 8; ++e) zs[j * 65 + k + e] = (float)v[e];
    }
}

__device__ __forceinline__ void up8(const float* zs, int base, float* u) {
    int h = base >> 7, w0 = base & 127;
    int j0 = h >> 1;
    int jn = (h & 1) ? min(j0 + 1, 63) : max(j0 - 1, 0);
    int K = w0 >> 1;
    float z0[6], z1[6];
    #pragma unroll
    for (int d = 0; d < 6; ++d) {
        int kc = min(max(K - 1 + d, 0), 63);
        z0[d] = zs[j0 * 65 + kc];
        z1[d] = zs[jn * 65 + kc];
    }
    #pragma unroll
    for (int e = 0; e < 8; ++e) {
        int a = (e >> 1) + 1;
        int bb = (e & 1) ? a + 1 : a - 1;
        u[e] = 0.5625f * z0[a] + 0.1875f * (z0[bb] + z1[a]) + 0.0625f * z1[bb];
    }
}

__global__ __launch_bounds__(256) void stats_k(const bf16* __restrict__ y1,
                                               const bf16* __restrict__ z,
                                               float* __restrict__ stats) {
    __shared__ float zs[64 * 65];
    __shared__ float red[8];
    const int bid = blockIdx.x;               // grid 2048 = b*256 + o
    const int o = bid & 255, b = bid >> 8;
    const int t = threadIdx.x;
    const bf16* zp = z + ((size_t)b * 256 + o) * 4096;
    const bf16* yp = y1 + ((size_t)b * 256 + o) * 16384;
    load_zplane(zp, zs, t);
    __syncthreads();
    float s = 0.f, ss = 0.f;
    for (int i = 0; i < 8; ++i) {
        int base = (i * 256 + t) * 8;
        float u[8];
        up8(zs, base, u);
        bf16x8 yv = *(const bf16x8*)(yp + base);
        #pragma unroll
        for (int e = 0; e < 8; ++e) {
            float y = (float)yv[e] + u[e];
            s += y; ss += y * y;
        }
    }
    #pragma unroll
    for (int off = 32; off > 0; off >>= 1) {
        s += __shfl_down(s, off);
        ss += __shfl_down(ss, off);
    }
    if ((t & 63) == 0) { red[t >> 6] = s; red[4 + (t >> 6)] = ss; }
    __syncthreads();
    if (t == 0) {
        atomicAdd(&stats[o],       red[0] + red[1] + red[2] + red[3]);
        atomicAdd(&stats[256 + o], red[4] + red[5] + red[6] + red[7]);
    }
}

// apply_k: finalize folded in (mean/var/scale/shift recomputed per block from
// the raw sums -- 2 scalar loads + ~6 ops, cheaper than a dispatch).
__global__ __launch_bounds__(256) void apply_k(const bf16* __restrict__ y1,
                                               const bf16* __restrict__ z,
                                               const float* __restrict__ stats,
                                               const float* __restrict__ gamma,
                                               const float* __restrict__ beta,
                                               float* __restrict__ out) {
    __shared__ float zs[64 * 65];
    const int bid = blockIdx.x;
    const int o = bid & 255, b = bid >> 8;
    const int t = threadIdx.x;
    const bf16* zp = z + ((size_t)b * 256 + o) * 4096;
    const bf16* yp = y1 + ((size_t)b * 256 + o) * 16384;
    float* op = out + ((size_t)b * 256 + o) * 16384;
    const float n = 131072.f;
    float mean = stats[o] / n;
    float var = stats[256 + o] / n - mean * mean;
    float sc = rsqrtf(var + 1e-5f) * gamma[o];
    float sh = beta[o] - mean * sc;
    load_zplane(zp, zs, t);
    __syncthreads();
    for (int i = 0; i < 8; ++i) {
        int base = (i * 256 + t) * 8;
        float u[8];
        up8(zs, base, u);
        bf16x8 yv = *(const bf16x8*)(yp + base);
        float4 o0, o1;
        o0.x = fmaxf(fmaf((float)yv[0] + u[0], sc, sh), 0.f);
        o0.y = fmaxf(fmaf((float)yv[1] + u[1], sc, sh), 0.f);
        o0.z = fmaxf(fmaf((float)yv[2] + u[2], sc, sh), 0.f);
        o0.w = fmaxf(fmaf((float)yv[3] + u[3], sc, sh), 0.f);
        o1.x = fmaxf(fmaf((float)yv[4] + u[4], sc, sh), 0.f);
        o1.y = fmaxf(fmaf((float)yv[5] + u[5], sc, sh), 0.f);
        o1.z = fmaxf(fmaf((float)yv[6] + u[6], sc, sh), 0.f);
        o1.w = fmaxf(fmaf((float)yv[7] + u[7], sc, sh), 0.f);
        *(float4*)(op + base) = o0;
        *(float4*)(op + base + 4) = o1;
    }
}

// ---------------------------------------------------------------------------
extern "C" void kernel_launch(void* const* d_in, const int* in_sizes, int n_in,
                              void* d_out, int out_size, void* d_ws, size_t ws_size,
                              hipStream_t stream) {
    const float* x      = (const float*)d_in[0];   // (8,256,128,128)
    const float* conv_w = (const float*)d_in[1];   // (256,1024)
    const float* gamma  = (const float*)d_in[2];   // (256,)
    const float* beta   = (const float*)d_in[3];   // (256,)
    float* out = (float*)d_out;

    char* ws = (char*)d_ws;
    // Wbf 640K (pad 1M) | z 16M | stats 4K (pad 64K) | y1 64M   (~81 MB)
    bf16*  Wbf   = (bf16*)ws;
    bf16*  z     = (bf16*)(ws + (1ll << 20));
    float* stats = (float*)(ws + (17ll << 20));
    bf16*  y1    = (bf16*)(ws + (17ll << 20) + (1ll << 16));

    hipMemsetAsync(stats, 0, 4096, stream);
    prep_w<<<256, 256, 0, stream>>>(conv_w, Wbf);
    fused_x<<<1024, 256, 0, stream>>>(x, Wbf, z, y1);
    stats_k<<<2048, 256, 0, stream>>>(y1, z, stats);
    apply_k<<<2048, 256, 0, stream>>>(y1, z, stats, gamma, beta, out);
}

// Round 3
// 347.072 us; speedup vs baseline: 1.2354x; 1.0188x over previous
//
#include <hip/hip_runtime.h>
#include <hip/hip_bf16.h>

typedef __bf16 bf16;
typedef __bf16 bf16x4 __attribute__((ext_vector_type(4)));
typedef __bf16 bf16x8 __attribute__((ext_vector_type(8)));
typedef float  f32x4  __attribute__((ext_vector_type(4)));

// ---------------------------------------------------------------------------
// prep_w: fold Haar linearity + W into bf16 weights.
// Wbf layout: [o][1280]:
//   cols 0:256            = W1 (identity path, y1 GEMM K=256)
//   cols 256+tap*256+c    = 0.5*(±W2 ±W3 ±W4)   tap: 0=p,1=q,2=r,3=s
// so z[o][coarse] = sum_{tap,c} Wf[o][tap*256+c] * x[c][fine(tap)]  (K=1024)
__global__ __launch_bounds__(256) void prep_w(const float* __restrict__ w,
                                              bf16* __restrict__ wb) {
    const int o = blockIdx.x, c = threadIdx.x;   // grid 256 x 256
    const float* wr = w + o * 1024;
    const float w1 = wr[c], w2 = wr[256 + c], w3 = wr[512 + c], w4 = wr[768 + c];
    bf16* wo_ = wb + o * 1280;
    wo_[c]              = (bf16)w1;
    wo_[256 + 0*256 + c] = (bf16)(0.5f * ( w2 + w3 + w4));   // p
    wo_[256 + 1*256 + c] = (bf16)(0.5f * ( w2 - w3 - w4));   // q
    wo_[256 + 2*256 + c] = (bf16)(0.5f * (-w2 + w3 - w4));   // r
    wo_[256 + 3*256 + c] = (bf16)(0.5f * (-w2 - w3 + w4));   // s
}

// ---------------------------------------------------------------------------
// LDS tile: 128 rows (fine pos = dlt*64 + w) x 256 c bf16, stride 256
// (64 KB exact). Bank spread via XOR of the 8-bf16 chunk index with
// g(row) = (row&7) ^ ((row>>2)&7).
__device__ __forceinline__ int tix(int row, int chunk, int lo) {
    int g = (row & 7) ^ ((row >> 2) & 7);
    return row * 256 + (((chunk ^ g) << 3) | lo);
}

// fused_x, 512-thread blocks (8 waves), 2 blocks/CU -> 16 waves/CU (4/SIMD,
// 2x round 2's 8/CU; that kernel was pure-latency-bound: MfmaUtil 9%,
// VALUBusy 5%, HBM 14%, all idle).
//   phase1: x fp32 -> LDS tile [128 pos][256 c] bf16 (reg transpose, b128)
//   phase2: y1 = W1 . tile  K=256; wave = 128 pos x 32 o: 16 MFMA : 2 W-loads
//   phase2b: y1 epilogue (frees 64-VGPR acc before phase3)
//   phase3: z = Wf . taps   K=1024; wave = 32 coarse x 32 o, depth-2 W
//           prefetch (4 MFMA/step can't hide L2 latency at depth 1)
__global__ __launch_bounds__(512, 4) void fused_x(const float* __restrict__ x,
                                                  const bf16* __restrict__ W,
                                                  bf16* __restrict__ z,
                                                  bf16* __restrict__ y1) {
    __shared__ bf16 tile[128 * 256];
    const int bid = blockIdx.x;               // grid 1024 = b*128 + j*2 + half
    const int half = bid & 1, j = (bid >> 1) & 63, b = bid >> 7;
    const int t = threadIdx.x;
    const int wave = t >> 6, lane = t & 63;
    const int quad = lane >> 4, l16 = lane & 15;
    const int wo2 = wave * 32;

    // phase1: 16 float4/thread in 2 bursts of 8 (8 channels per burst)
    #pragma unroll
    for (int it = 0; it < 2; ++it) {
        const int a   = it * 512 + t;        // 0..1023 assignments
        const int c8  = a >> 5;              // chunk of 8 consecutive channels
        const int rem = a & 31;
        const int dlt = rem >> 4, w4 = rem & 15;
        const float* xp = x + (((size_t)b * 256 + c8 * 8) * 128 + (2*j + dlt)) * 128
                            + half * 64 + w4 * 4;
        float4 v[8];
        #pragma unroll
        for (int i = 0; i < 8; ++i)
            v[i] = *(const float4*)(xp + (size_t)i * 16384);   // next channel
        #pragma unroll
        for (int e = 0; e < 4; ++e) {
            bf16x8 o8;
            #pragma unroll
            for (int i = 0; i < 8; ++i) o8[i] = (bf16)((&v[i].x)[e]);
            const int pos = dlt * 64 + w4 * 4 + e;
            *(bf16x8*)&tile[tix(pos, c8, 0)] = o8;
        }
    }

    // prefetch W1 fragments for kk=0 (L2-resident; latency hidden by barrier)
    bf16x8 wf_cur[2], wf_nxt[2];
    #pragma unroll
    for (int jj = 0; jj < 2; ++jj)
        wf_cur[jj] = *(const bf16x8*)(W +
            (size_t)(wo2 + jj * 16 + l16) * 1280 + quad * 8);

    __syncthreads();

    // phase2: y1 GEMM. wave = 128 pos x 32 o. MFMA(xf, wf): D.row=pos, D.col=o
    {
        f32x4 acc[8][2] = {};
        #pragma unroll
        for (int kk = 0; kk < 256; kk += 32) {
            if (kk < 224) {
                #pragma unroll
                for (int jj = 0; jj < 2; ++jj)
                    wf_nxt[jj] = *(const bf16x8*)(W +
                        (size_t)(wo2 + jj * 16 + l16) * 1280 + kk + 32 + quad * 8);
            } else {
                // seed the z-loop pipeline: first Wf fragments (cols 256..)
                #pragma unroll
                for (int jj = 0; jj < 2; ++jj)
                    wf_nxt[jj] = *(const bf16x8*)(W +
                        (size_t)(wo2 + jj * 16 + l16) * 1280 + 256 + quad * 8);
            }
            const int kc0 = kk >> 3;
            #pragma unroll
            for (int i2 = 0; i2 < 8; ++i2) {
                const bf16x8 xf = *(const bf16x8*)&tile[tix(i2 * 16 + l16,
                                                            kc0 + quad, 0)];
                #pragma unroll
                for (int jj = 0; jj < 2; ++jj)
                    acc[i2][jj] = __builtin_amdgcn_mfma_f32_16x16x32_bf16(
                        xf, wf_cur[jj], acc[i2][jj], 0, 0, 0);
            }
            #pragma unroll
            for (int jj = 0; jj < 2; ++jj) wf_cur[jj] = wf_nxt[jj];
        }

        // depth-2 seed for phase3 (col 288); latency hides under y1 epilogue
        #pragma unroll
        for (int jj = 0; jj < 2; ++jj)
            wf_nxt[jj] = *(const bf16x8*)(W +
                (size_t)(wo2 + jj * 16 + l16) * 1280 + 256 + 32 + quad * 8);

        // y1 epilogue: pos = i2*16 + quad*4 + r, o = wo2 + jj*16 + l16
        #pragma unroll
        for (int i2 = 0; i2 < 8; ++i2) {
            int p = i2 * 16 + quad * 4;
            int h = 2 * j + (p >> 6), wc = half * 64 + (p & 63);
            #pragma unroll
            for (int jj = 0; jj < 2; ++jj) {
                int o = wo2 + jj * 16 + l16;
                bf16x4 vv;
                #pragma unroll
                for (int r = 0; r < 4; ++r) vv[r] = (bf16)acc[i2][jj][r];
                *(bf16x4*)(y1 + ((size_t)b * 256 + o) * 16384 + h * 128 + wc) = vv;
            }
        }
    }

    // phase3: z GEMM, K=1024 over (tap, c). m = 32 coarse cols (this half).
    // tap->fine: p=(dlt0,even w) q=(dlt0,odd) r=(dlt1,even) s=(dlt1,odd)
    // depth-2 pipeline: wf_cur = kz, wf_nxt = kz+32, load kz+64 each step.
    f32x4 acc2[2][2] = {};
    #pragma unroll
    for (int kz = 0; kz < 1024; kz += 32) {
        bf16x8 wf_nx2[2];
        if (kz < 960) {
            #pragma unroll
            for (int jj = 0; jj < 2; ++jj)
                wf_nx2[jj] = *(const bf16x8*)(W +
                    (size_t)(wo2 + jj * 16 + l16) * 1280 + 256 + kz + 64 + quad * 8);
        }
        const int tap = kz >> 8;
        const int dlt = tap >> 1, par = tap & 1;
        const int kc0 = (kz & 255) >> 3;
        bf16x8 af[2];
        #pragma unroll
        for (int mi = 0; mi < 2; ++mi)
            af[mi] = *(const bf16x8*)&tile[tix(dlt * 64 + 2 * (mi * 16 + l16) + par,
                                               kc0 + quad, 0)];
        #pragma unroll
        for (int mi = 0; mi < 2; ++mi)
            #pragma unroll
            for (int jj = 0; jj < 2; ++jj)
                acc2[mi][jj] = __builtin_amdgcn_mfma_f32_16x16x32_bf16(
                    af[mi], wf_cur[jj], acc2[mi][jj], 0, 0, 0);
        #pragma unroll
        for (int jj = 0; jj < 2; ++jj) { wf_cur[jj] = wf_nxt[jj]; wf_nxt[jj] = wf_nx2[jj]; }
    }

    // epilogue z: coarse col = half*32 + mi*16 + quad*4 + r, coarse row = j
    #pragma unroll
    for (int mi = 0; mi < 2; ++mi) {
        #pragma unroll
        for (int jj = 0; jj < 2; ++jj) {
            int o = wo2 + jj * 16 + l16;
            int cw = half * 32 + mi * 16 + quad * 4;
            bf16x4 vv;
            #pragma unroll
            for (int r = 0; r < 4; ++r) vv[r] = (bf16)acc2[mi][jj][r];
            *(bf16x4*)(z + ((size_t)b * 256 + o) * 4096 + j * 64 + cw) = vv;
        }
    }
}

// ---------------------------------------------------------------------------
// Bilinear 2x upsample weights: 0.75/0.25 per axis, edge-clamped (== jax).
// zs row stride 68: keeps float4 alignment (k multiple of 8, 68%4==0) and
// shifts banks by 4/row.
#define ZS 68

__device__ __forceinline__ void load_zplane(const bf16* zp, float* zs, int t) {
    #pragma unroll
    for (int i = 0; i < 2; ++i) {
        int idx = (i * 256 + t) * 8;
        int j = idx >> 6, k = idx & 63;
        bf16x8 v = *(const bf16x8*)(zp + idx);
        float4 a, bq;
        a.x  = (float)v[0]; a.y  = (float)v[1]; a.z  = (float)v[2]; a.w  = (float)v[3];
        bq.x = (float)v[4]; bq.y = (float)v[5]; bq.z = (float)v[6]; bq.w = (float)v[7];
        *(float4*)&zs[j * ZS + k]     = a;
        *(float4*)&zs[j * ZS + k + 4] = bq;
    }
}

__device__ __forceinline__ void up8(const float* zs, int base, float* u) {
    int h = base >> 7, w0 = base & 127;
    int j0 = h >> 1;
    int jn = (h & 1) ? min(j0 + 1, 63) : max(j0 - 1, 0);
    int K = w0 >> 1;
    const float* r0 = zs + j0 * ZS;
    const float* r1 = zs + jn * ZS;
    float z0[6], z1[6];
    #pragma unroll
    for (int d = 0; d < 6; ++d) {
        int kc = min(max(K - 1 + d, 0), 63);
        z0[d] = r0[kc];
        z1[d] = r1[kc];
    }
    #pragma unroll
    for (int e = 0; e < 8; ++e) {
        int a = (e >> 1) + 1;
        int bb = (e & 1) ? a + 1 : a - 1;
        u[e] = 0.5625f * z0[a] + 0.1875f * (z0[bb] + z1[a]) + 0.0625f * z1[bb];
    }
}

__global__ __launch_bounds__(256) void stats_k(const bf16* __restrict__ y1,
                                               const bf16* __restrict__ z,
                                               float* __restrict__ stats) {
    __shared__ float zs[64 * ZS];
    __shared__ float red[8];
    const int bid = blockIdx.x;               // grid 2048 = b*256 + o
    const int o = bid & 255, b = bid >> 8;
    const int t = threadIdx.x;
    const bf16* zp = z + ((size_t)b * 256 + o) * 4096;
    const bf16* yp = y1 + ((size_t)b * 256 + o) * 16384;
    load_zplane(zp, zs, t);
    // batch-issue all y loads (8x16B in flight) before the barrier wait
    bf16x8 yv[8];
    #pragma unroll
    for (int i = 0; i < 8; ++i)
        yv[i] = *(const bf16x8*)(yp + (i * 256 + t) * 8);
    __syncthreads();
    float s = 0.f, ss = 0.f;
    #pragma unroll
    for (int i = 0; i < 8; ++i) {
        int base = (i * 256 + t) * 8;
        float u[8];
        up8(zs, base, u);
        #pragma unroll
        for (int e = 0; e < 8; ++e) {
            float y = (float)yv[i][e] + u[e];
            s += y; ss += y * y;
        }
    }
    #pragma unroll
    for (int off = 32; off > 0; off >>= 1) {
        s += __shfl_down(s, off);
        ss += __shfl_down(ss, off);
    }
    if ((t & 63) == 0) { red[t >> 6] = s; red[4 + (t >> 6)] = ss; }
    __syncthreads();
    if (t == 0) {
        atomicAdd(&stats[o],       red[0] + red[1] + red[2] + red[3]);
        atomicAdd(&stats[256 + o], red[4] + red[5] + red[6] + red[7]);
    }
}

// apply_k: finalize folded in (mean/var/scale/shift recomputed per block from
// the raw sums -- 2 scalar loads + ~6 ops, cheaper than a dispatch).
__global__ __launch_bounds__(256) void apply_k(const bf16* __restrict__ y1,
                                               const bf16* __restrict__ z,
                                               const float* __restrict__ stats,
                                               const float* __restrict__ gamma,
                                               const float* __restrict__ beta,
                                               float* __restrict__ out) {
    __shared__ float zs[64 * ZS];
    const int bid = blockIdx.x;
    const int o = bid & 255, b = bid >> 8;
    const int t = threadIdx.x;
    const bf16* zp = z + ((size_t)b * 256 + o) * 4096;
    const bf16* yp = y1 + ((size_t)b * 256 + o) * 16384;
    float* op = out + ((size_t)b * 256 + o) * 16384;
    const float n = 131072.f;
    float mean = stats[o] / n;
    float var = stats[256 + o] / n - mean * mean;
    float sc = rsqrtf(var + 1e-5f) * gamma[o];
    float sh = beta[o] - mean * sc;
    load_zplane(zp, zs, t);
    bf16x8 yv[8];
    #pragma unroll
    for (int i = 0; i < 8; ++i)
        yv[i] = *(const bf16x8*)(yp + (i * 256 + t) * 8);
    __syncthreads();
    #pragma unroll
    for (int i = 0; i < 8; ++i) {
        int base = (i * 256 + t) * 8;
        float u[8];
        up8(zs, base, u);
        float4 o0, o1;
        o0.x = fmaxf(fmaf((float)yv[i][0] + u[0], sc, sh), 0.f);
        o0.y = fmaxf(fmaf((float)yv[i][1] + u[1], sc, sh), 0.f);
        o0.z = fmaxf(fmaf((float)yv[i][2] + u[2], sc, sh), 0.f);
        o0.w = fmaxf(fmaf((float)yv[i][3] + u[3], sc, sh), 0.f);
        o1.x = fmaxf(fmaf((float)yv[i][4] + u[4], sc, sh), 0.f);
        o1.y = fmaxf(fmaf((float)yv[i][5] + u[5], sc, sh), 0.f);
        o1.z = fmaxf(fmaf((float)yv[i][6] + u[6], sc, sh), 0.f);
        o1.w = fmaxf(fmaf((float)yv[i][7] + u[7], sc, sh), 0.f);
        *(float4*)(op + base) = o0;
        *(float4*)(op + base + 4) = o1;
    }
}

// ---------------------------------------------------------------------------
extern "C" void kernel_launch(void* const* d_in, const int* in_sizes, int n_in,
                              void* d_out, int out_size, void* d_ws, size_t ws_size,
                              hipStream_t stream) {
    const float* x      = (const float*)d_in[0];   // (8,256,128,128)
    const float* conv_w = (const float*)d_in[1];   // (256,1024)
    const float* gamma  = (const float*)d_in[2];   // (256,)
    const float* beta   = (const float*)d_in[3];   // (256,)
    float* out = (float*)d_out;

    char* ws = (char*)d_ws;
    // Wbf 640K (pad 1M) | z 16M | stats 4K (pad 64K) | y1 64M   (~81 MB)
    bf16*  Wbf   = (bf16*)ws;
    bf16*  z     = (bf16*)(ws + (1ll << 20));
    float* stats = (float*)(ws + (17ll << 20));
    bf16*  y1    = (bf16*)(ws + (17ll << 20) + (1ll << 16));

    hipMemsetAsync(stats, 0, 4096, stream);
    prep_w<<<256, 256, 0, stream>>>(conv_w, Wbf);
    fused_x<<<1024, 512, 0, stream>>>(x, Wbf, z, y1);
    stats_k<<<2048, 256, 0, stream>>>(y1, z, stats);
    apply_k<<<2048, 256, 0, stream>>>(y1, z, stats, gamma, beta, out);
}